// Round 4
// baseline (1069.192 us; speedup 1.0000x reference)
//
#include <hip/hip_runtime.h>
#include <math.h>

#define B_ 4
#define C_ 256
#define RES_ 128
#define HW_ 16384
#define WF_ 65
#define F_ 8320

__device__ __forceinline__ int brev7(int j){ return (int)(__brev((unsigned)j) >> 25); }

// ---- band id, bit-exact vs numpy float32 (no FMA contraction) ----
__device__ __forceinline__ int band_of(int row, int col){
  float yy = __fdiv_rn((float)row, 127.0f);
  float xx = __fdiv_rn((float)col, 64.0f);
  float rr = __fsqrt_rn(__fadd_rn(__fmul_rn(yy,yy), __fmul_rn(xx,xx)));
  float rm = __fadd_rn(__fsqrt_rn(2.0f), 1e-8f);
  float rn = __fdiv_rn(rr, rm);
  int b = (int)floorf(__fmul_rn(rn, 6.0f));
  return b > 5 ? 5 : b;
}

__device__ __forceinline__ float sigmoidf_(float v){ return 1.0f/(1.0f+expf(-v)); }

// ---- in-LDS radix-2 DIF FFT, length 128 ----
template<int SGN, int NROWS>
__device__ __forceinline__ void fft128_lds(float2* buf, int rstride, int tid, const float2* tw){
  const int total = NROWS*64;
  #pragma unroll
  for (int stage=0; stage<7; stage++){
    int half = 64 >> stage;
    __syncthreads();
    for (int idx = tid; idx < total; idx += 256){
      int row = idx % NROWS;
      int t   = idx / NROWS;
      int j   = t & (half-1);
      int i0  = ((t >> (6-stage)) << (7-stage)) + j;
      int i1  = i0 + half;
      float2* rb = buf + row*rstride;
      float2 a = rb[i0], b = rb[i1];
      float2 w = tw[j << stage];
      float dx = a.x - b.x, dy = a.y - b.y;
      rb[i0] = make_float2(a.x+b.x, a.y+b.y);
      float ws = (SGN < 0) ? -w.y : w.y;
      rb[i1] = make_float2(dx*w.x - dy*ws, dx*ws + dy*w.x);
    }
  }
  __syncthreads();
}

// ---- (B,HW,C) -> (B,C,HW) transpose ----
__global__ __launch_bounds__(1024) void k_transpose(const float* __restrict__ x, float* __restrict__ x2){
  __shared__ float tile[64][65];
  int b = blockIdx.z;
  int hw0 = blockIdx.x*64, c0 = blockIdx.y*64;
  int tx = threadIdx.x, ty = threadIdx.y;
  #pragma unroll
  for (int i=0;i<4;i++){
    int hw = hw0 + ty + i*16;
    tile[ty+i*16][tx] = x[((size_t)b*HW_ + hw)*C_ + c0 + tx];
  }
  __syncthreads();
  #pragma unroll
  for (int i=0;i<4;i++){
    int c = c0 + ty + i*16;
    x2[((size_t)b*C_ + c)*HW_ + hw0 + tx] = tile[tx][ty+i*16];
  }
}

// ---- counts + band-id table ----
__global__ __launch_bounds__(256) void k_counts(float* __restrict__ counts, unsigned char* __restrict__ bid){
  int tid = threadIdx.x;
  float acc[6] = {0,0,0,0,0,0};
  for (int f = tid; f < F_; f += 256){
    int row = f / WF_, col = f - row*WF_;
    int bnd = band_of(row, col);
    bid[f] = (unsigned char)bnd;
    #pragma unroll
    for (int n=0;n<6;n++) acc[n] += (bnd==n) ? 1.0f : 0.0f;
  }
  __shared__ float red[6][256];
  #pragma unroll
  for (int n=0;n<6;n++) red[n][tid] = acc[n];
  __syncthreads();
  for (int s=128; s>0; s>>=1){
    if (tid < s){
      #pragma unroll
      for (int n=0;n<6;n++) red[n][tid] += red[n][tid+s];
    }
    __syncthreads();
  }
  if (tid < 6) counts[tid] = fmaxf(red[tid][0], 1.0f);
}

// ---- forward row rFFT: x2 -> X1 ----
__global__ __launch_bounds__(256) void k_fwd_rows(const float* __restrict__ x2, float2* __restrict__ X1){
  __shared__ float2 buf[32*129];
  __shared__ float2 tw[64];
  int tid = threadIdx.x;
  if (tid < 64){ float s,c; sincosf(6.283185307179586f*(float)tid/128.0f,&s,&c); tw[tid]=make_float2(c,s); }
  int slice = blockIdx.x >> 2;
  int r0 = (blockIdx.x & 3) * 32;
  const float4* src = (const float4*)(x2 + (size_t)slice*HW_ + (size_t)r0*128);
  #pragma unroll
  for (int q=0; q<4; q++){
    int f4 = tid + 256*q;
    float4 v = src[f4];
    int pos = f4*4;
    int row = pos >> 7, i = pos & 127;
    float2* rb = buf + row*129 + i;
    rb[0] = make_float2(v.x, 0.0f);
    rb[1] = make_float2(v.y, 0.0f);
    rb[2] = make_float2(v.z, 0.0f);
    rb[3] = make_float2(v.w, 0.0f);
  }
  fft128_lds<-1,32>(buf, 129, tid, tw);
  float2* dst = X1 + (size_t)slice*F_ + (size_t)r0*WF_;
  for (int p = tid; p < 32*WF_; p += 256){
    int row = p / WF_, k = p - row*WF_;
    dst[p] = buf[row*129 + brev7(k)];
  }
}

// ---- forward col FFT + ortho scale + band-gate ----
__global__ __launch_bounds__(256) void k_fwd_cols_gate(const float2* __restrict__ X1, float2* __restrict__ Xf,
                                                       const float* __restrict__ counts, const unsigned char* __restrict__ bid,
                                                       const float* __restrict__ w1, const float* __restrict__ b1,
                                                       const float* __restrict__ w2, const float* __restrict__ b2,
                                                       float* __restrict__ alpha){
  __shared__ float2 cbuf[13*129];
  __shared__ float2 tw[64];
  __shared__ float red[6][256];
  __shared__ float means[6], h[128];
  int tid = threadIdx.x;
  if (tid < 64){ float s,c; sincosf(6.283185307179586f*(float)tid/128.0f,&s,&c); tw[tid]=make_float2(c,s); }
  int slice = blockIdx.x;
  const float2* xin = X1 + (size_t)slice*F_;
  float2* xout = Xf + (size_t)slice*F_;
  float acc[6] = {0,0,0,0,0,0};
  for (int chunk=0; chunk<5; chunk++){
    int c0 = chunk*13;
    __syncthreads();
    for (int p = tid; p < 13*128; p += 256){
      int y = p / 13, col = p - y*13;
      cbuf[col*129 + y] = xin[y*WF_ + c0 + col];
    }
    fft128_lds<-1,13>(cbuf, 129, tid, tw);
    for (int p = tid; p < 13*128; p += 256){
      int ky = p / 13, col = p - ky*13, kx = c0 + col;
      float2 v = cbuf[col*129 + brev7(ky)];
      v.x *= 0.0078125f; v.y *= 0.0078125f;
      int f = ky*WF_ + kx;
      xout[f] = v;
      float m = __fsqrt_rn(v.x*v.x + v.y*v.y);
      int bb = (int)bid[f];
      #pragma unroll
      for (int n=0;n<6;n++) acc[n] += (bb==n) ? m : 0.0f;
    }
  }
  __syncthreads();
  #pragma unroll
  for (int n=0;n<6;n++) red[n][tid] = acc[n];
  __syncthreads();
  for (int s=128; s>0; s>>=1){
    if (tid < s){
      #pragma unroll
      for (int n=0;n<6;n++) red[n][tid] += red[n][tid+s];
    }
    __syncthreads();
  }
  if (tid < 6) means[tid] = red[tid][0] / (counts[tid] + 1e-6f);
  __syncthreads();
  if (tid < 128){
    float hv = b1[tid];
    #pragma unroll
    for (int n=0;n<6;n++) hv += means[n]*w1[tid*6+n];
    h[tid] = fmaxf(hv, 0.0f);
  }
  __syncthreads();
  if (tid < 6){
    float o = b2[tid];
    for (int j=0;j<128;j++) o += h[j]*w2[tid*128+j];
    alpha[slice*6 + tid] = sigmoidf_(o);
  }
}

// ---- pointwise channel GEMM: 64c x 256hw per block, thread 8x8 ----
__global__ __launch_bounds__(256) void k_pointwise(const float* __restrict__ x2, const float* __restrict__ lw,
                                                   const float* __restrict__ lb, float* __restrict__ xcs){
  __shared__ float Ws[16][64];
  __shared__ float Xs[16][256];
  int tid = threadIdx.x;
  int b = blockIdx.z, c0 = blockIdx.y*64, hw0 = blockIdx.x*256;
  int tx = tid & 31, ty = tid >> 5;
  float acc[8][8];
  #pragma unroll
  for (int i=0;i<8;i++)
    #pragma unroll
    for (int j=0;j<8;j++) acc[i][j] = 0.0f;
  for (int dt=0; dt<16; dt++){
    int d0 = dt*16;
    __syncthreads();
    #pragma unroll
    for (int q=0;q<4;q++){
      int p = tid + q*256;
      int dl = p & 15, cl = p >> 4;
      Ws[dl][cl] = lw[(c0+cl)*C_ + d0+dl];
      int dl2 = p >> 6, hwl4 = (p & 63)*4;
      *(float4*)&Xs[dl2][hwl4] = *(const float4*)&x2[((size_t)(b*C_+d0+dl2))*HW_ + hw0 + hwl4];
    }
    __syncthreads();
    #pragma unroll
    for (int dl=0; dl<16; dl++){
      float4 w0 = *(float4*)&Ws[dl][ty*8];
      float4 w1 = *(float4*)&Ws[dl][ty*8+4];
      float4 xa = *(float4*)&Xs[dl][tx*4];        // hw lo half
      float4 xb = *(float4*)&Xs[dl][128 + tx*4];  // hw hi half
      float wv[8] = {w0.x,w0.y,w0.z,w0.w,w1.x,w1.y,w1.z,w1.w};
      float xv[8] = {xa.x,xa.y,xa.z,xa.w,xb.x,xb.y,xb.z,xb.w};
      #pragma unroll
      for (int i=0;i<8;i++)
        #pragma unroll
        for (int j=0;j<8;j++) acc[i][j] += wv[i]*xv[j];
    }
  }
  #pragma unroll
  for (int i=0;i<8;i++){
    int c = c0 + ty*8 + i;
    float bias = lb[c];
    float4 lo = make_float4(acc[i][0]+bias, acc[i][1]+bias, acc[i][2]+bias, acc[i][3]+bias);
    float4 hi = make_float4(acc[i][4]+bias, acc[i][5]+bias, acc[i][6]+bias, acc[i][7]+bias);
    float* base = xcs + ((size_t)(b*C_+c))*HW_ + hw0;
    *(float4*)(base + tx*4)       = lo;
    *(float4*)(base + 128 + tx*4) = hi;
  }
}

// ---- complex channel mix, tiled: 64c x 64f(8ky x 8kx) per block ----
__global__ __launch_bounds__(256) void k_mix(const float2* __restrict__ Xf, const float* __restrict__ wre,
                                             const float* __restrict__ wim, const float* __restrict__ kxp,
                                             const float* __restrict__ kyp, float2* __restrict__ mapped){
  int rt = blockIdx.x >> 3, ct = blockIdx.x & 7;   // 16 row-tiles x 8 col-tiles
  int ky0 = rt*8, kx0 = ct*8;
  float rowlim = floorf(sigmoidf_(kxp[0])*128.0f);
  float collim = floorf(sigmoidf_(kyp[0])*65.0f);
  if (!((float)ky0 < rowlim) || !((float)kx0 < collim)) return;
  int b = blockIdx.z, c0 = blockIdx.y*64;
  __shared__ float Wre[16][64], Wim[16][64];
  __shared__ float2 Xs[16][64];
  int tid = threadIdx.x;
  int tx = tid & 15, ty = tid >> 4;
  float ar[4][4], ai[4][4];
  #pragma unroll
  for (int i=0;i<4;i++)
    #pragma unroll
    for (int j=0;j<4;j++){ ar[i][j]=0.0f; ai[i][j]=0.0f; }
  const float2* xb = Xf + (size_t)b*C_*F_;
  for (int dt=0; dt<16; dt++){
    int d0 = dt*16;
    __syncthreads();
    #pragma unroll
    for (int q=0;q<4;q++){
      int p = tid + q*256;
      int dl = p & 15, cl = p >> 4;
      Wre[dl][cl] = wre[(c0+cl)*C_ + d0+dl];
      Wim[dl][cl] = wim[(c0+cl)*C_ + d0+dl];
      int fl = p & 63, dl2 = p >> 6;
      int ry = fl >> 3, cx = fl & 7;
      int f = (ky0+ry)*WF_ + kx0+cx;
      if (f > F_-1) f = F_-1;
      Xs[dl2][fl] = xb[(size_t)(d0+dl2)*F_ + f];
    }
    __syncthreads();
    #pragma unroll
    for (int dl=0; dl<16; dl++){
      float4 wr4 = *(float4*)&Wre[dl][ty*4];
      float4 wi4 = *(float4*)&Wim[dl][ty*4];
      float4 va = *(float4*)&Xs[dl][tx*2];        // f-locals tx*2, tx*2+1
      float4 vb = *(float4*)&Xs[dl][32 + tx*2];   // f-locals 32+tx*2, +1
      float wrv[4] = {wr4.x,wr4.y,wr4.z,wr4.w};
      float wiv[4] = {wi4.x,wi4.y,wi4.z,wi4.w};
      float vx[4] = {va.x,va.z,vb.x,vb.z};
      float vy[4] = {va.y,va.w,vb.y,vb.w};
      #pragma unroll
      for (int i=0;i<4;i++)
        #pragma unroll
        for (int j=0;j<4;j++){
          ar[i][j] += wrv[i]*vx[j] - wiv[i]*vy[j];
          ai[i][j] += wrv[i]*vy[j] + wiv[i]*vx[j];
        }
    }
  }
  #pragma unroll
  for (int i=0;i<4;i++){
    int c = c0 + ty*4 + i;
    float2* mb = mapped + (size_t)(b*C_+c)*F_;
    #pragma unroll
    for (int j=0;j<4;j++){
      int fl = (j < 2) ? (tx*2 + j) : (32 + tx*2 + (j-2));
      int ry = fl >> 3, cx = fl & 7;
      int ky = ky0 + ry, kx = kx0 + cx;
      if (((float)ky < rowlim) && ((float)kx < collim))
        mb[ky*WF_ + kx] = make_float2(ar[i][j], ai[i][j]);
    }
  }
}

// ---- inverse col FFT with fused alpha-blend; in place over mapped ----
__global__ __launch_bounds__(256) void k_inv_cols(const float2* __restrict__ Xf, const float2* __restrict__ mapped,
                                                  const float* __restrict__ alpha, const unsigned char* __restrict__ bid,
                                                  const float* __restrict__ kxp, const float* __restrict__ kyp,
                                                  float2* __restrict__ Y1){
  __shared__ float2 cbuf[13*129];
  __shared__ float2 tw[64];
  __shared__ float al[6];
  int tid = threadIdx.x;
  int chunk = blockIdx.x, slice = blockIdx.y;
  int c0 = chunk*13;
  if (tid < 64){ float s,c; sincosf(6.283185307179586f*(float)tid/128.0f,&s,&c); tw[tid]=make_float2(c,s); }
  if (tid < 6) al[tid] = alpha[slice*6 + tid];
  float rowlim = floorf(sigmoidf_(kxp[0])*128.0f);
  float collim = floorf(sigmoidf_(kyp[0])*65.0f);
  __syncthreads();
  const float2* xfb = Xf + (size_t)slice*F_;
  const float2* mpb = mapped + (size_t)slice*F_;
  for (int p = tid; p < 13*128; p += 256){
    int ky = p / 13, col = p - ky*13, kx = c0 + col;
    int f = ky*WF_ + kx;
    float a = al[(int)bid[f]];
    bool inm = ((float)ky < rowlim) && ((float)kx < collim);
    float2 v;
    if (inm){ v = mpb[f]; v.x *= a; v.y *= a; }
    else    { v = xfb[f]; float om = 1.0f - a; v.x *= om; v.y *= om; }
    cbuf[col*129 + ky] = v;
  }
  fft128_lds<1,13>(cbuf, 129, tid, tw);
  float2* yb = Y1 + (size_t)slice*F_;
  for (int p = tid; p < 13*128; p += 256){
    int y = p / 13, col = p - y*13;
    yb[y*WF_ + c0 + col] = cbuf[col*129 + brev7(y)];
  }
}

// ---- inverse row c2r + depthwise 3x3 conv (fused) + xcs -> sbuf ----
__global__ __launch_bounds__(256) void k_inv_rows(const float2* __restrict__ Y1, const float* __restrict__ xcs,
                                                  const float* __restrict__ x2, const float* __restrict__ cw,
                                                  float* __restrict__ sbuf){
  __shared__ float2 buf[32*129];
  __shared__ float2 tw[64];
  __shared__ float ct[34*128];
  int tid = threadIdx.x;
  if (tid < 64){ float s,c; sincosf(6.283185307179586f*(float)tid/128.0f,&s,&c); tw[tid]=make_float2(c,s); }
  int slice = blockIdx.x >> 2;
  int ch = slice & 255;
  int r0 = (blockIdx.x & 3) * 32;
  const float* img = x2 + (size_t)slice*HW_;
  #pragma unroll
  for (int q=0;q<17;q++){
    int p = tid + q*256;
    int row = p >> 7, xx = p & 127;
    int sr = r0 - 1 + row;
    ct[p] = ((unsigned)sr < 128u) ? img[sr*128+xx] : 0.0f;
  }
  float w9[9];
  #pragma unroll
  for (int k=0;k<9;k++) w9[k] = cw[ch*9+k];
  const float2* src = Y1 + (size_t)slice*F_ + (size_t)r0*WF_;
  for (int p = tid; p < 32*WF_; p += 256){
    int row = p / WF_, k = p - row*WF_;
    float2 v = src[p];
    if (k == 0 || k == 64) v.y = 0.0f;
    buf[row*129 + k] = v;
    if (k >= 1 && k <= 63) buf[row*129 + 128 - k] = make_float2(v.x, -v.y);
  }
  fft128_lds<1,32>(buf, 129, tid, tw);
  size_t gbase = (size_t)slice*HW_ + (size_t)r0*128;
  for (int p = tid; p < 32*128; p += 256){
    int row = p >> 7, xx = p & 127;
    float conv = 0.0f;
    #pragma unroll
    for (int dy=0; dy<3; dy++){
      const float* cr = &ct[(row+dy)*128];
      float l = (xx>0)   ? cr[xx-1] : 0.0f;
      float m = cr[xx];
      float r = (xx<127) ? cr[xx+1] : 0.0f;
      conv += l*w9[dy*3+0] + m*w9[dy*3+1] + r*w9[dy*3+2];
    }
    size_t g = gbase + p;
    sbuf[g] = buf[row*129 + brev7(xx)].x * 0.0078125f + xcs[g] + conv;
  }
}

// ---- LN stats over channels ----
__global__ __launch_bounds__(256) void k_stats(const float* __restrict__ sbuf, float* __restrict__ stats){
  int g = blockIdx.x*256 + threadIdx.x;
  int b = g >> 14, hw = g & 16383;
  const float* p = sbuf + (size_t)b*C_*HW_ + hw;
  float s1 = 0.0f, s2 = 0.0f;
  for (int c=0; c<C_; c++){
    float v = p[(size_t)c*HW_];
    s1 += v; s2 += v*v;
  }
  float mean = s1 * (1.0f/256.0f);
  float var  = s2 * (1.0f/256.0f) - mean*mean;
  stats[g] = mean;
  stats[65536 + g] = 1.0f / sqrtf(var + 1e-5f);
}

// ---- LN apply + cond scale/shift, coalesced transpose to (B,HW,C) ----
__global__ __launch_bounds__(256) void k_apply(const float* __restrict__ sbuf, const float* __restrict__ stats,
                                               const float* __restrict__ timev,
                                               const float* __restrict__ nww, const float* __restrict__ nwb,
                                               const float* __restrict__ nbw, const float* __restrict__ nbb,
                                               float* __restrict__ out){
  __shared__ float tile[64][65];
  __shared__ float wv[64], bv[64], mv[64], rv[64];
  int b = blockIdx.z, c0 = blockIdx.y*64, hw0 = blockIdx.x*64;
  int tid = threadIdx.x;
  if (tid < 64){
    float t = timev[b];
    int c = c0 + tid;
    wv[tid] = t*nww[c] + nwb[c];
    bv[tid] = t*nbw[c] + nbb[c];
    mv[tid] = stats[(b<<14) + hw0 + tid];
    rv[tid] = stats[65536 + (b<<14) + hw0 + tid];
  }
  #pragma unroll
  for (int q=0;q<16;q++){
    int p = tid + q*256;
    int cl = p >> 6, hwl = p & 63;
    tile[cl][hwl] = sbuf[((size_t)(b*C_+c0+cl))*HW_ + hw0 + hwl];
  }
  __syncthreads();
  #pragma unroll
  for (int q=0;q<16;q++){
    int p = tid + q*256;
    int hwl = p >> 6, cl = p & 63;
    float v = tile[cl][hwl];
    out[((size_t)(b*HW_+hw0+hwl))*C_ + c0 + cl] = wv[cl]*((v - mv[hwl])*rv[hwl]) + bv[cl];
  }
}

extern "C" void kernel_launch(void* const* d_in, const int* in_sizes, int n_in,
                              void* d_out, int out_size, void* d_ws, size_t ws_size,
                              hipStream_t stream){
  const float* x      = (const float*)d_in[0];
  const float* timev  = (const float*)d_in[1];
  const float* w_real = (const float*)d_in[2];
  const float* w_imag = (const float*)d_in[3];
  const float* conv_w = (const float*)d_in[4];
  const float* lin_w  = (const float*)d_in[5];
  const float* lin_b  = (const float*)d_in[6];
  const float* mlp_w1 = (const float*)d_in[7];
  const float* mlp_b1 = (const float*)d_in[8];
  const float* mlp_w2 = (const float*)d_in[9];
  const float* mlp_b2 = (const float*)d_in[10];
  const float* norm_ww= (const float*)d_in[11];
  const float* norm_wb= (const float*)d_in[12];
  const float* norm_bw= (const float*)d_in[13];
  const float* norm_bb= (const float*)d_in[14];
  const float* kxp    = (const float*)d_in[15];
  const float* kyp    = (const float*)d_in[16];

  // workspace layout (floats) — total 50,999,360 floats = 194.6 MiB (unchanged footprint)
  float* ws = (float*)d_ws;
  float*  alpha = ws;                               // 6144
  unsigned char* bid = (unsigned char*)(ws + 6144); // 8320 B
  float*  counts= ws + 12288;                       // 8 (padded)
  float*  stats = ws + 12352;                       // 131072 (mean | rstd)
  float*  x2    = ws + 143424;                      // 16,777,216 (stays live for conv)
  float2* Xf    = (float2*)(ws + 16920640);         // 8,519,680 f2; region reused as sbuf after inv_cols
  float2* Cb    = (float2*)(ws + 33960000);         // 8,519,680 f2 (X1 -> mapped -> Y1 in place)
  float*  sb    = (float*)Xf;                       // 16.7M floats fit in Xf region (17.0M)
  float*  xcs   = (float*)d_out;                    // pointwise output, scratch in d_out
  float*  out   = (float*)d_out;

  k_transpose    <<<dim3(256, 4, B_), dim3(64,16), 0, stream>>>(x, x2);
  k_counts       <<<1, 256, 0, stream>>>(counts, bid);
  k_fwd_rows     <<<4096, 256, 0, stream>>>(x2, Cb);
  k_fwd_cols_gate<<<1024, 256, 0, stream>>>(Cb, Xf, counts, bid, mlp_w1, mlp_b1, mlp_w2, mlp_b2, alpha);
  k_pointwise    <<<dim3(64, 4, B_), 256, 0, stream>>>(x2, lin_w, lin_b, xcs);
  k_mix          <<<dim3(128, 4, B_), 256, 0, stream>>>(Xf, w_real, w_imag, kxp, kyp, Cb);
  k_inv_cols     <<<dim3(5, 1024), 256, 0, stream>>>(Xf, Cb, alpha, bid, kxp, kyp, Cb);
  k_inv_rows     <<<4096, 256, 0, stream>>>(Cb, xcs, x2, conv_w, sb);
  k_stats        <<<256, 256, 0, stream>>>(sb, stats);
  k_apply        <<<dim3(256, 4, B_), 256, 0, stream>>>(sb, stats, timev, norm_ww, norm_wb, norm_bw, norm_bb, out);
}

// Round 5
// 570.288 us; speedup vs baseline: 1.8748x; 1.8748x over previous
//
#include <hip/hip_runtime.h>
#include <math.h>

#define B_ 4
#define C_ 256
#define RES_ 128
#define HW_ 16384
#define WF_ 65
#define F_ 8320
#define FP_ 2880   // packed masked-freq grid: 72 rows x 40 cols (covers runtime 71x36)

typedef __attribute__((ext_vector_type(8))) short bf16x8;
typedef __attribute__((ext_vector_type(16))) float f32x16;

__device__ __forceinline__ int brev7(int j){ return (int)(__brev((unsigned)j) >> 25); }

__device__ __forceinline__ short f2bf(float f){
  unsigned u = __float_as_uint(f);
  unsigned r = (u + 0x7FFFu + ((u>>16)&1u)) >> 16;
  return (short)r;
}

__device__ __forceinline__ bf16x8 lds_frag(const short* p){
  union { bf16x8 v; int2 d[2]; } u;
  u.d[0] = *(const int2*)p;
  u.d[1] = *(const int2*)(p+4);
  return u.v;
}
__device__ __forceinline__ void lds_store8(short* p, bf16x8 v){
  union { bf16x8 v; int2 d[2]; } u; u.v = v;
  *(int2*)p = u.d[0]; *(int2*)(p+4) = u.d[1];
}

// ---- band id, bit-exact vs numpy float32 ----
__device__ __forceinline__ int band_of(int row, int col){
  float yy = __fdiv_rn((float)row, 127.0f);
  float xx = __fdiv_rn((float)col, 64.0f);
  float rr = __fsqrt_rn(__fadd_rn(__fmul_rn(yy,yy), __fmul_rn(xx,xx)));
  float rm = __fadd_rn(__fsqrt_rn(2.0f), 1e-8f);
  float rn = __fdiv_rn(rr, rm);
  int b = (int)floorf(__fmul_rn(rn, 6.0f));
  return b > 5 ? 5 : b;
}

__device__ __forceinline__ float sigmoidf_(float v){ return 1.0f/(1.0f+expf(-v)); }

// ---- in-LDS radix-2 DIF FFT, length 128 ----
template<int SGN, int NROWS>
__device__ __forceinline__ void fft128_lds(float2* buf, int rstride, int tid, const float2* tw){
  const int total = NROWS*64;
  #pragma unroll
  for (int stage=0; stage<7; stage++){
    int half = 64 >> stage;
    __syncthreads();
    for (int idx = tid; idx < total; idx += 256){
      int row = idx % NROWS;
      int t   = idx / NROWS;
      int j   = t & (half-1);
      int i0  = ((t >> (6-stage)) << (7-stage)) + j;
      int i1  = i0 + half;
      float2* rb = buf + row*rstride;
      float2 a = rb[i0], b = rb[i1];
      float2 w = tw[j << stage];
      float dx = a.x - b.x, dy = a.y - b.y;
      rb[i0] = make_float2(a.x+b.x, a.y+b.y);
      float ws = (SGN < 0) ? -w.y : w.y;
      rb[i1] = make_float2(dx*w.x - dy*ws, dx*ws + dy*w.x);
    }
  }
  __syncthreads();
}

// ---- (B,HW,C) -> (B,C,HW) transpose ----
__global__ __launch_bounds__(1024) void k_transpose(const float* __restrict__ x, float* __restrict__ x2){
  __shared__ float tile[64][65];
  int b = blockIdx.z;
  int hw0 = blockIdx.x*64, c0 = blockIdx.y*64;
  int tx = threadIdx.x, ty = threadIdx.y;
  #pragma unroll
  for (int i=0;i<4;i++){
    int hw = hw0 + ty + i*16;
    tile[ty+i*16][tx] = x[((size_t)b*HW_ + hw)*C_ + c0 + tx];
  }
  __syncthreads();
  #pragma unroll
  for (int i=0;i<4;i++){
    int c = c0 + ty + i*16;
    x2[((size_t)b*C_ + c)*HW_ + hw0 + tx] = tile[tx][ty+i*16];
  }
}

// ---- counts + band-id table ----
__global__ __launch_bounds__(256) void k_counts(float* __restrict__ counts, unsigned char* __restrict__ bid){
  int tid = threadIdx.x;
  float acc[6] = {0,0,0,0,0,0};
  for (int f = tid; f < F_; f += 256){
    int row = f / WF_, col = f - row*WF_;
    int bnd = band_of(row, col);
    bid[f] = (unsigned char)bnd;
    #pragma unroll
    for (int n=0;n<6;n++) acc[n] += (bnd==n) ? 1.0f : 0.0f;
  }
  __shared__ float red[6][256];
  #pragma unroll
  for (int n=0;n<6;n++) red[n][tid] = acc[n];
  __syncthreads();
  for (int s=128; s>0; s>>=1){
    if (tid < s){
      #pragma unroll
      for (int n=0;n<6;n++) red[n][tid] += red[n][tid+s];
    }
    __syncthreads();
  }
  if (tid < 6) counts[tid] = fmaxf(red[tid][0], 1.0f);
}

// ---- convert W matrices to bf16 planes ----
__global__ __launch_bounds__(256) void k_wbf16(const float* __restrict__ wre, const float* __restrict__ wim,
                                               const float* __restrict__ lw,
                                               short* __restrict__ Wre, short* __restrict__ Wim,
                                               short* __restrict__ WL){
  int c = blockIdx.x, tid = threadIdx.x, plane = blockIdx.y;
  int idx = c*C_ + tid;
  if (plane == 0)      Wre[idx] = f2bf(wre[idx]);
  else if (plane == 1) Wim[idx] = f2bf(wim[idx]);
  else                 WL[idx]  = f2bf(lw[idx]);
}

// ---- forward row rFFT: x2 -> X1 ----
__global__ __launch_bounds__(256) void k_fwd_rows(const float* __restrict__ x2, float2* __restrict__ X1){
  __shared__ float2 buf[32*129];
  __shared__ float2 tw[64];
  int tid = threadIdx.x;
  if (tid < 64){ float s,c; sincosf(6.283185307179586f*(float)tid/128.0f,&s,&c); tw[tid]=make_float2(c,s); }
  int slice = blockIdx.x >> 2;
  int r0 = (blockIdx.x & 3) * 32;
  const float4* src = (const float4*)(x2 + (size_t)slice*HW_ + (size_t)r0*128);
  #pragma unroll
  for (int q=0; q<4; q++){
    int f4 = tid + 256*q;
    float4 v = src[f4];
    int pos = f4*4;
    int row = pos >> 7, i = pos & 127;
    float2* rb = buf + row*129 + i;
    rb[0] = make_float2(v.x, 0.0f);
    rb[1] = make_float2(v.y, 0.0f);
    rb[2] = make_float2(v.z, 0.0f);
    rb[3] = make_float2(v.w, 0.0f);
  }
  fft128_lds<-1,32>(buf, 129, tid, tw);
  float2* dst = X1 + (size_t)slice*F_ + (size_t)r0*WF_;
  for (int p = tid; p < 32*WF_; p += 256){
    int row = p / WF_, k = p - row*WF_;
    dst[p] = buf[row*129 + brev7(k)];
  }
}

// ---- forward col FFT + ortho scale + band-gate ----
__global__ __launch_bounds__(256) void k_fwd_cols_gate(const float2* __restrict__ X1, float2* __restrict__ Xf,
                                                       const float* __restrict__ counts, const unsigned char* __restrict__ bid,
                                                       const float* __restrict__ w1, const float* __restrict__ b1,
                                                       const float* __restrict__ w2, const float* __restrict__ b2,
                                                       float* __restrict__ alpha){
  __shared__ float2 cbuf[13*129];
  __shared__ float2 tw[64];
  __shared__ float red[6][256];
  __shared__ float means[6], h[128];
  int tid = threadIdx.x;
  if (tid < 64){ float s,c; sincosf(6.283185307179586f*(float)tid/128.0f,&s,&c); tw[tid]=make_float2(c,s); }
  int slice = blockIdx.x;
  const float2* xin = X1 + (size_t)slice*F_;
  float2* xout = Xf + (size_t)slice*F_;
  float acc[6] = {0,0,0,0,0,0};
  for (int chunk=0; chunk<5; chunk++){
    int c0 = chunk*13;
    __syncthreads();
    for (int p = tid; p < 13*128; p += 256){
      int y = p / 13, col = p - y*13;
      cbuf[col*129 + y] = xin[y*WF_ + c0 + col];
    }
    fft128_lds<-1,13>(cbuf, 129, tid, tw);
    for (int p = tid; p < 13*128; p += 256){
      int ky = p / 13, col = p - ky*13, kx = c0 + col;
      float2 v = cbuf[col*129 + brev7(ky)];
      v.x *= 0.0078125f; v.y *= 0.0078125f;
      int f = ky*WF_ + kx;
      xout[f] = v;
      float m = __fsqrt_rn(v.x*v.x + v.y*v.y);
      int bb = (int)bid[f];
      #pragma unroll
      for (int n=0;n<6;n++) acc[n] += (bb==n) ? m : 0.0f;
    }
  }
  __syncthreads();
  #pragma unroll
  for (int n=0;n<6;n++) red[n][tid] = acc[n];
  __syncthreads();
  for (int s=128; s>0; s>>=1){
    if (tid < s){
      #pragma unroll
      for (int n=0;n<6;n++) red[n][tid] += red[n][tid+s];
    }
    __syncthreads();
  }
  if (tid < 6) means[tid] = red[tid][0] / (counts[tid] + 1e-6f);
  __syncthreads();
  if (tid < 128){
    float hv = b1[tid];
    #pragma unroll
    for (int n=0;n<6;n++) hv += means[n]*w1[tid*6+n];
    h[tid] = fmaxf(hv, 0.0f);
  }
  __syncthreads();
  if (tid < 6){
    float o = b2[tid];
    for (int j=0;j<128;j++) o += h[j]*w2[tid*128+j];
    alpha[slice*6 + tid] = sigmoidf_(o);
  }
}

// ---- pack+transpose Xf (static 72x40 region) -> Xt planes [b][fp][d] bf16 ----
__global__ __launch_bounds__(256) void k_xt(const float2* __restrict__ Xf,
                                            short* __restrict__ XtRe, short* __restrict__ XtIm){
  __shared__ float2 tile[40][129];
  int tid = threadIdx.x;
  int ky = blockIdx.x, d0 = blockIdx.y*128, b = blockIdx.z;
  const float2* xb = Xf + ((size_t)(b*C_ + d0))*F_ + ky*WF_;
  #pragma unroll
  for (int i=0;i<20;i++){
    int p = tid + i*256;
    int d = p / 40, kx = p - d*40;
    tile[kx][d] = xb[(size_t)d*F_ + kx];
  }
  __syncthreads();
  #pragma unroll
  for (int i=0;i<20;i++){
    int p = tid + i*256;
    int kx = p >> 7, d = p & 127;
    float2 v = tile[kx][d];
    size_t o = ((size_t)b*FP_ + ky*40 + kx)*C_ + d0 + d;
    XtRe[o] = f2bf(v.x);
    XtIm[o] = f2bf(v.y);
  }
}

// ---- MFMA complex channel mix: mappedP[c][fp] = sum_d W[c][d] * X[fp][d] ----
__global__ __launch_bounds__(256) void k_mix_mfma(const short* __restrict__ Wre, const short* __restrict__ Wim,
                                                  const short* __restrict__ XtRe, const short* __restrict__ XtIm,
                                                  const float* __restrict__ kxp, const float* __restrict__ kyp,
                                                  float2* __restrict__ mappedP){
  __shared__ short Are[64][36], Aim[64][36], Bre[64][36], Bim[64][36];
  int tid = threadIdx.x;
  int fp0 = blockIdx.x*64, c0 = blockIdx.y*64, b = blockIdx.z;
  int lane = tid & 63, w = tid >> 6;
  int mt = (w >> 1)*32, nt = (w & 1)*32;
  f32x16 accre = {0.f,0.f,0.f,0.f,0.f,0.f,0.f,0.f,0.f,0.f,0.f,0.f,0.f,0.f,0.f,0.f};
  f32x16 accim = {0.f,0.f,0.f,0.f,0.f,0.f,0.f,0.f,0.f,0.f,0.f,0.f,0.f,0.f,0.f,0.f};
  const short* xrb = XtRe + ((size_t)b*FP_ + fp0)*C_;
  const short* xib = XtIm + ((size_t)b*FP_ + fp0)*C_;
  int row4 = tid >> 2, part = tid & 3;
  for (int kc=0; kc<8; kc++){
    int d0 = kc*32;
    __syncthreads();
    lds_store8(&Are[row4][part*8], *(const bf16x8*)&Wre[(c0+row4)*C_ + d0 + part*8]);
    lds_store8(&Aim[row4][part*8], *(const bf16x8*)&Wim[(c0+row4)*C_ + d0 + part*8]);
    lds_store8(&Bre[row4][part*8], *(const bf16x8*)&xrb[(size_t)row4*C_ + d0 + part*8]);
    lds_store8(&Bim[row4][part*8], *(const bf16x8*)&xib[(size_t)row4*C_ + d0 + part*8]);
    __syncthreads();
    #pragma unroll
    for (int ks=0; ks<2; ks++){
      int koff = ks*16 + (lane>>5)*8;
      bf16x8 are = lds_frag(&Are[mt + (lane&31)][koff]);
      bf16x8 aim = lds_frag(&Aim[mt + (lane&31)][koff]);
      bf16x8 bre = lds_frag(&Bre[nt + (lane&31)][koff]);
      bf16x8 bim = lds_frag(&Bim[nt + (lane&31)][koff]);
      bf16x8 naim;
      { union { bf16x8 v; unsigned u[4]; } t1, t2; t1.v = aim;
        #pragma unroll
        for (int j=0;j<4;j++) t2.u[j] = t1.u[j] ^ 0x80008000u;
        naim = t2.v; }
      accre = __builtin_amdgcn_mfma_f32_32x32x16_bf16(are,  bre, accre, 0,0,0);
      accre = __builtin_amdgcn_mfma_f32_32x32x16_bf16(naim, bim, accre, 0,0,0);
      accim = __builtin_amdgcn_mfma_f32_32x32x16_bf16(are,  bim, accim, 0,0,0);
      accim = __builtin_amdgcn_mfma_f32_32x32x16_bf16(aim,  bre, accim, 0,0,0);
    }
  }
  float rowlim = floorf(sigmoidf_(kxp[0])*128.0f);
  float collim = floorf(sigmoidf_(kyp[0])*65.0f);
  int n = fp0 + nt + (lane & 31);
  int ky = n / 40, kx = n - ky*40;
  bool live = ((float)ky < rowlim) && ((float)kx < collim);
  #pragma unroll
  for (int reg=0; reg<16; reg++){
    int r = (reg & 3) + 8*(reg >> 2) + 4*(lane >> 5);
    int c = c0 + mt + r;
    if (live)
      mappedP[((size_t)(b*C_ + c))*FP_ + n] = make_float2(accre[reg], accim[reg]);
  }
}

// ---- MFMA pointwise: xcs[c][hw] = sum_d lin_w[c][d] * x[hw][d] + lin_b[c] ----
__global__ __launch_bounds__(256) void k_pw_mfma(const float* __restrict__ x, const short* __restrict__ WL,
                                                  const float* __restrict__ lb, float* __restrict__ xcs){
  __shared__ short As[64][36], Bs[64][36];
  int tid = threadIdx.x;
  int hw0 = blockIdx.x*64, c0 = blockIdx.y*64, b = blockIdx.z;
  int lane = tid & 63, w = tid >> 6;
  int mt = (w >> 1)*32, nt = (w & 1)*32;
  f32x16 acc = {0.f,0.f,0.f,0.f,0.f,0.f,0.f,0.f,0.f,0.f,0.f,0.f,0.f,0.f,0.f,0.f};
  const float* xb = x + ((size_t)b*HW_ + hw0)*C_;
  int row4 = tid >> 2, part = tid & 3;
  for (int kc=0; kc<8; kc++){
    int d0 = kc*32;
    __syncthreads();
    lds_store8(&As[row4][part*8], *(const bf16x8*)&WL[(c0+row4)*C_ + d0 + part*8]);
    {
      const float* src = &xb[(size_t)row4*C_ + d0 + part*8];
      float4 va = *(const float4*)src;
      float4 vb = *(const float4*)(src+4);
      bf16x8 bv;
      bv[0]=f2bf(va.x); bv[1]=f2bf(va.y); bv[2]=f2bf(va.z); bv[3]=f2bf(va.w);
      bv[4]=f2bf(vb.x); bv[5]=f2bf(vb.y); bv[6]=f2bf(vb.z); bv[7]=f2bf(vb.w);
      lds_store8(&Bs[row4][part*8], bv);
    }
    __syncthreads();
    #pragma unroll
    for (int ks=0; ks<2; ks++){
      int koff = ks*16 + (lane>>5)*8;
      bf16x8 a  = lds_frag(&As[mt + (lane&31)][koff]);
      bf16x8 bb = lds_frag(&Bs[nt + (lane&31)][koff]);
      acc = __builtin_amdgcn_mfma_f32_32x32x16_bf16(a, bb, acc, 0,0,0);
    }
  }
  int n = hw0 + nt + (lane & 31);
  #pragma unroll
  for (int reg=0; reg<16; reg++){
    int r = (reg & 3) + 8*(reg >> 2) + 4*(lane >> 5);
    int c = c0 + mt + r;
    xcs[((size_t)(b*C_ + c))*HW_ + n] = acc[reg] + lb[c];
  }
}

// ---- inverse col FFT with fused alpha-blend; Y1 written in place into Xf region ----
__global__ __launch_bounds__(256) void k_inv_cols(float2* __restrict__ XfY, const float2* __restrict__ mappedP,
                                                  const float* __restrict__ alpha, const unsigned char* __restrict__ bid,
                                                  const float* __restrict__ kxp, const float* __restrict__ kyp){
  __shared__ float2 cbuf[13*129];
  __shared__ float2 tw[64];
  __shared__ float al[6];
  int tid = threadIdx.x;
  int chunk = blockIdx.x, slice = blockIdx.y;
  int c0 = chunk*13;
  if (tid < 64){ float s,c; sincosf(6.283185307179586f*(float)tid/128.0f,&s,&c); tw[tid]=make_float2(c,s); }
  if (tid < 6) al[tid] = alpha[slice*6 + tid];
  float rowlim = floorf(sigmoidf_(kxp[0])*128.0f);
  float collim = floorf(sigmoidf_(kyp[0])*65.0f);
  __syncthreads();
  float2* xfb = XfY + (size_t)slice*F_;
  const float2* mpb = mappedP + (size_t)slice*FP_;
  for (int p = tid; p < 13*128; p += 256){
    int ky = p / 13, col = p - ky*13, kx = c0 + col;
    int f = ky*WF_ + kx;
    float a = al[(int)bid[f]];
    bool inm = ((float)ky < rowlim) && ((float)kx < collim);
    float2 v;
    if (inm){ v = mpb[ky*40 + kx]; v.x *= a; v.y *= a; }
    else    { v = xfb[f]; float om = 1.0f - a; v.x *= om; v.y *= om; }
    cbuf[col*129 + ky] = v;
  }
  fft128_lds<1,13>(cbuf, 129, tid, tw);
  for (int p = tid; p < 13*128; p += 256){
    int y = p / 13, col = p - y*13;
    xfb[y*WF_ + c0 + col] = cbuf[col*129 + brev7(y)];
  }
}

// ---- inverse row c2r + fused depthwise 3x3 conv + xcs -> sbuf ----
__global__ __launch_bounds__(256) void k_inv_rows(const float2* __restrict__ Y1, const float* __restrict__ xcs,
                                                  const float* __restrict__ x2, const float* __restrict__ cw,
                                                  float* __restrict__ sbuf){
  __shared__ float2 buf[32*129];
  __shared__ float2 tw[64];
  __shared__ float ct[34*128];
  int tid = threadIdx.x;
  if (tid < 64){ float s,c; sincosf(6.283185307179586f*(float)tid/128.0f,&s,&c); tw[tid]=make_float2(c,s); }
  int slice = blockIdx.x >> 2;
  int ch = slice & 255;
  int r0 = (blockIdx.x & 3) * 32;
  const float* img = x2 + (size_t)slice*HW_;
  #pragma unroll
  for (int q=0;q<17;q++){
    int p = tid + q*256;
    int row = p >> 7, xx = p & 127;
    int sr = r0 - 1 + row;
    ct[p] = ((unsigned)sr < 128u) ? img[sr*128+xx] : 0.0f;
  }
  float w9[9];
  #pragma unroll
  for (int k=0;k<9;k++) w9[k] = cw[ch*9+k];
  const float2* src = Y1 + (size_t)slice*F_ + (size_t)r0*WF_;
  for (int p = tid; p < 32*WF_; p += 256){
    int row = p / WF_, k = p - row*WF_;
    float2 v = src[p];
    if (k == 0 || k == 64) v.y = 0.0f;
    buf[row*129 + k] = v;
    if (k >= 1 && k <= 63) buf[row*129 + 128 - k] = make_float2(v.x, -v.y);
  }
  fft128_lds<1,32>(buf, 129, tid, tw);
  size_t gbase = (size_t)slice*HW_ + (size_t)r0*128;
  for (int p = tid; p < 32*128; p += 256){
    int row = p >> 7, xx = p & 127;
    float conv = 0.0f;
    #pragma unroll
    for (int dy=0; dy<3; dy++){
      const float* cr = &ct[(row+dy)*128];
      float l = (xx>0)   ? cr[xx-1] : 0.0f;
      float m = cr[xx];
      float r = (xx<127) ? cr[xx+1] : 0.0f;
      conv += l*w9[dy*3+0] + m*w9[dy*3+1] + r*w9[dy*3+2];
    }
    size_t g = gbase + p;
    sbuf[g] = buf[row*129 + brev7(xx)].x * 0.0078125f + xcs[g] + conv;
  }
}

// ---- LN stats over channels ----
__global__ __launch_bounds__(256) void k_stats(const float* __restrict__ sbuf, float* __restrict__ stats){
  int g = blockIdx.x*256 + threadIdx.x;
  int b = g >> 14, hw = g & 16383;
  const float* p = sbuf + (size_t)b*C_*HW_ + hw;
  float s1 = 0.0f, s2 = 0.0f;
  for (int c=0; c<C_; c++){
    float v = p[(size_t)c*HW_];
    s1 += v; s2 += v*v;
  }
  float mean = s1 * (1.0f/256.0f);
  float var  = s2 * (1.0f/256.0f) - mean*mean;
  stats[g] = mean;
  stats[65536 + g] = 1.0f / sqrtf(var + 1e-5f);
}

// ---- LN apply + cond scale/shift, coalesced transpose to (B,HW,C) ----
__global__ __launch_bounds__(256) void k_apply(const float* __restrict__ sbuf, const float* __restrict__ stats,
                                               const float* __restrict__ timev,
                                               const float* __restrict__ nww, const float* __restrict__ nwb,
                                               const float* __restrict__ nbw, const float* __restrict__ nbb,
                                               float* __restrict__ out){
  __shared__ float tile[64][65];
  __shared__ float wv[64], bv[64], mv[64], rv[64];
  int b = blockIdx.z, c0 = blockIdx.y*64, hw0 = blockIdx.x*64;
  int tid = threadIdx.x;
  if (tid < 64){
    float t = timev[b];
    int c = c0 + tid;
    wv[tid] = t*nww[c] + nwb[c];
    bv[tid] = t*nbw[c] + nbb[c];
    mv[tid] = stats[(b<<14) + hw0 + tid];
    rv[tid] = stats[65536 + (b<<14) + hw0 + tid];
  }
  #pragma unroll
  for (int q=0;q<16;q++){
    int p = tid + q*256;
    int cl = p >> 6, hwl = p & 63;
    tile[cl][hwl] = sbuf[((size_t)(b*C_+c0+cl))*HW_ + hw0 + hwl];
  }
  __syncthreads();
  #pragma unroll
  for (int q=0;q<16;q++){
    int p = tid + q*256;
    int hwl = p >> 6, cl = p & 63;
    float v = tile[cl][hwl];
    out[((size_t)(b*HW_+hw0+hwl))*C_ + c0 + cl] = wv[cl]*((v - mv[hwl])*rv[hwl]) + bv[cl];
  }
}

extern "C" void kernel_launch(void* const* d_in, const int* in_sizes, int n_in,
                              void* d_out, int out_size, void* d_ws, size_t ws_size,
                              hipStream_t stream){
  const float* x      = (const float*)d_in[0];
  const float* timev  = (const float*)d_in[1];
  const float* w_real = (const float*)d_in[2];
  const float* w_imag = (const float*)d_in[3];
  const float* conv_w = (const float*)d_in[4];
  const float* lin_w  = (const float*)d_in[5];
  const float* lin_b  = (const float*)d_in[6];
  const float* mlp_w1 = (const float*)d_in[7];
  const float* mlp_b1 = (const float*)d_in[8];
  const float* mlp_w2 = (const float*)d_in[9];
  const float* mlp_b2 = (const float*)d_in[10];
  const float* norm_ww= (const float*)d_in[11];
  const float* norm_wb= (const float*)d_in[12];
  const float* norm_bw= (const float*)d_in[13];
  const float* norm_bb= (const float*)d_in[14];
  const float* kxp    = (const float*)d_in[15];
  const float* kyp    = (const float*)d_in[16];

  // workspace layout (floats) — total 51,093,600 floats = 194.9 MiB
  float* ws = (float*)d_ws;
  float*  alpha  = ws;                               // 6144
  unsigned char* bid = (unsigned char*)(ws + 6144);  // 8320 B (2080 floats)
  float*  counts = ws + 8224;                        // 64
  float*  stats  = ws + 8288;                        // 131072
  short*  Wre_bf = (short*)(ws + 139360);            // 65536 shorts (32768 floats)
  short*  Wim_bf = (short*)(ws + 172128);            // 65536 shorts
  short*  WL_bf  = (short*)(ws + 204896);            // 65536 shorts
  float*  x2     = ws + 237664;                      // 16,777,216 (live until inv_rows: conv input)
  float2* Xf     = (float2*)(ws + 17014880);         // 17,039,360 floats (Xf, then Y1 in-place)
  float*  CbF    = ws + 34054240;                    // 17,039,360 floats, multi-use:
  float2* X1     = (float2*)CbF;                     //   X1 (fwd FFT intermediate, dead after fwd_cols_gate)
  short*  XtRe   = (short*)CbF;                      //   then Xt bf16 planes [b][2880][256]
  short*  XtIm   = (short*)(CbF + 1474560);
  float2* mappedP= (float2*)(CbF + 2949120);         //   packed mapped [b][c][2880] (5,898,240 floats)
  float*  sb     = CbF;                              //   then final sum (16,777,216) after inv_cols
  float*  xcs    = (float*)d_out;                    // pointwise output, scratch in d_out
  float*  out    = (float*)d_out;

  k_transpose    <<<dim3(256, 4, B_), dim3(64,16), 0, stream>>>(x, x2);
  k_counts       <<<1, 256, 0, stream>>>(counts, bid);
  k_wbf16        <<<dim3(256, 3), 256, 0, stream>>>(w_real, w_imag, lin_w, Wre_bf, Wim_bf, WL_bf);
  k_fwd_rows     <<<4096, 256, 0, stream>>>(x2, X1);
  k_fwd_cols_gate<<<1024, 256, 0, stream>>>(X1, Xf, counts, bid, mlp_w1, mlp_b1, mlp_w2, mlp_b2, alpha);
  k_xt           <<<dim3(72, 2, B_), 256, 0, stream>>>(Xf, XtRe, XtIm);
  k_pw_mfma      <<<dim3(256, 4, B_), 256, 0, stream>>>(x, WL_bf, lin_b, xcs);
  k_mix_mfma     <<<dim3(45, 4, B_), 256, 0, stream>>>(Wre_bf, Wim_bf, XtRe, XtIm, kxp, kyp, mappedP);
  k_inv_cols     <<<dim3(5, 1024), 256, 0, stream>>>(Xf, mappedP, alpha, bid, kxp, kyp);
  k_inv_rows     <<<4096, 256, 0, stream>>>((const float2*)Xf, xcs, x2, conv_w, sb);
  k_stats        <<<256, 256, 0, stream>>>(sb, stats);
  k_apply        <<<dim3(256, 4, B_), 256, 0, stream>>>(sb, stats, timev, norm_ww, norm_wb, norm_bw, norm_bb, out);
}